// Round 4
// baseline (100.786 us; speedup 1.0000x reference)
//
#include <hip/hip_runtime.h>
#include <hip/hip_bf16.h>

#define S_DIM 2048
#define G_DIM 8
#define D_DIM 128
#define N_ROWS (S_DIM * G_DIM)   // 16384
#define SCALE 30.0f
#define NSPLIT 16
#define TCHUNK (S_DIM / NSPLIT)  // 128 -> 8 t-tiles of 16 per wave

typedef __attribute__((ext_vector_type(8))) short bf16x8;
typedef __attribute__((ext_vector_type(4))) float f32x4;

__device__ __forceinline__ float wave_allreduce_sum(float v) {
    #pragma unroll
    for (int m = 32; m >= 1; m >>= 1) v += __shfl_xor(v, m, 64);
    return v;
}

__device__ __forceinline__ short f2bf(float f) {
    __hip_bfloat16 h = __float2bfloat16(f);
    return *reinterpret_cast<short*>(&h);
}

// ---------------------------------------------------------------------------
// Kernel A: centroids (bf16, normalized) + exclusive-centroid cosine (fp32).
// xn itself is NOT materialized anymore — score_kernel re-normalizes its own
// A-rows from fp32 x (saves a 4MB write + 4MB read and a dependency).
// One block per speaker s; 8 waves = 8 utterances; lane handles dims l, l+64.
// ---------------------------------------------------------------------------
__global__ __launch_bounds__(512) void prep_kernel(
    const float* __restrict__ x,          // [S][G][D]
    __hip_bfloat16* __restrict__ centb,   // [S][D]
    float* __restrict__ cosexc)           // [S*G]
{
    __shared__ float xs[G_DIM][D_DIM];
    __shared__ float csum[D_DIM];

    const int s    = blockIdx.x;
    const int g    = threadIdx.x >> 6;
    const int lane = threadIdx.x & 63;
    const int d0 = lane, d1 = lane + 64;

    const float* xr = x + (s * G_DIM + g) * D_DIM;
    float a0 = xr[d0], a1 = xr[d1];

    // row L2 normalize (clip 1e-12)
    float ss  = wave_allreduce_sum(a0 * a0 + a1 * a1);
    float inv = 1.0f / fmaxf(sqrtf(ss), 1e-12f);
    float x0 = a0 * inv, x1 = a1 * inv;

    xs[g][d0] = x0;
    xs[g][d1] = x1;
    __syncthreads();

    // column sums over g
    if (threadIdx.x < D_DIM) {
        float c = 0.0f;
        #pragma unroll
        for (int gg = 0; gg < G_DIM; ++gg) c += xs[gg][threadIdx.x];
        csum[threadIdx.x] = c;
    }
    __syncthreads();

    // exclusive centroid: (sum - xn)/(G-1), normalize (clip 1e-8), cosine w/ xn
    float e0 = (csum[d0] - x0) * (1.0f / (G_DIM - 1));
    float e1 = (csum[d1] - x1) * (1.0f / (G_DIM - 1));
    float ess = wave_allreduce_sum(e0 * e0 + e1 * e1);
    float ed  = fmaxf(sqrtf(ess), 1e-8f);
    float dot = wave_allreduce_sum(x0 * e0 + x1 * e1);
    if (lane == 0) cosexc[s * G_DIM + g] = dot / ed;

    // centroid: cent = csum/8, cent_n = cent / clip(||cent||, 1e-8)
    if (g == 0) {
        float c0 = csum[d0], c1 = csum[d1];
        float css  = wave_allreduce_sum(c0 * c0 + c1 * c1);
        float cnrm = sqrtf(css) * (1.0f / G_DIM);          // ||cent||
        float scl  = (1.0f / G_DIM) / fmaxf(cnrm, 1e-8f);
        centb[s * D_DIM + d0] = __float2bfloat16(c0 * scl);
        centb[s * D_DIM + d1] = __float2bfloat16(c1 * scl);
    }
}

// ---------------------------------------------------------------------------
// Kernel B: fused normalize + scores + softmax-denominator.
// 64 rows/wave (4 A-tiles resident); per t-tile 4 B-loads feed 16 MFMAs in
// 4 independent chains. Grid 64 x NSPLIT=16 = 1024 blocks = 4/CU.
// A rows are normalized IN-KERNEL from fp32 x: each lane holds 32 k-elems of
// row (row0+m*16+nIdx); quads 0..3 of the same nIdx hold disjoint k-ranges,
// so shfl_xor(16)+shfl_xor(32) gives the full row sum-of-squares.
// A-frag (16x16x32): A[m=lane&15][k=(lane>>4)*8+j]. C/D: col=lane&15,
// row=(lane>>4)*4+reg [m89-verified].
// Diagonal band (8 speakers/wave, 8-aligned) hits exactly one 16-t tile ->
// wave-uniform branch; plab written once by the owning split.
// logsumexp offset fixed at 30 (logits in (0,30]): no max pass.
// ---------------------------------------------------------------------------
__global__ __launch_bounds__(256, 4) void score_kernel(
    const float* __restrict__ x,               // [N_ROWS][D] fp32
    const __hip_bfloat16* __restrict__ centb,  // [S][D]
    const float* __restrict__ cosexc,          // [N_ROWS]
    float* __restrict__ psum,                  // [NSPLIT][N_ROWS] partial sum-exp
    float* __restrict__ plab)                  // [N_ROWS] label logit (single owner)
{
    const int wave  = threadIdx.x >> 6;
    const int lane  = threadIdx.x & 63;
    const int row0  = (blockIdx.x * 4 + wave) * 64;   // 64 rows per wave
    const int split = blockIdx.y;
    const int tbase = split * TCHUNK;
    const int nIdx  = lane & 15;
    const int quad  = lane >> 4;
    const int s0    = row0 >> 3;                      // first speaker of this wave

    // A fragments: load fp32, normalize, convert to bf16, keep resident
    bf16x8 afrag[4][4];
    #pragma unroll
    for (int m = 0; m < 4; ++m) {
        const float* xr = x + (size_t)(row0 + m * 16 + nIdx) * D_DIM + quad * 8;
        float4 va[4], vb[4];
        float ss = 0.0f;
        #pragma unroll
        for (int kc = 0; kc < 4; ++kc) {
            va[kc] = *(const float4*)(xr + kc * 32);
            vb[kc] = *(const float4*)(xr + kc * 32 + 4);
            ss += va[kc].x * va[kc].x + va[kc].y * va[kc].y
                + va[kc].z * va[kc].z + va[kc].w * va[kc].w
                + vb[kc].x * vb[kc].x + vb[kc].y * vb[kc].y
                + vb[kc].z * vb[kc].z + vb[kc].w * vb[kc].w;
        }
        ss += __shfl_xor(ss, 16, 64);
        ss += __shfl_xor(ss, 32, 64);
        const float inv = 1.0f / fmaxf(sqrtf(ss), 1e-12f);
        #pragma unroll
        for (int kc = 0; kc < 4; ++kc) {
            bf16x8 t;
            t[0] = f2bf(va[kc].x * inv); t[1] = f2bf(va[kc].y * inv);
            t[2] = f2bf(va[kc].z * inv); t[3] = f2bf(va[kc].w * inv);
            t[4] = f2bf(vb[kc].x * inv); t[5] = f2bf(vb[kc].y * inv);
            t[6] = f2bf(vb[kc].z * inv); t[7] = f2bf(vb[kc].w * inv);
            afrag[m][kc] = t;
        }
    }

    float sumexp[4][4];
    #pragma unroll
    for (int m = 0; m < 4; ++m)
        #pragma unroll
        for (int r = 0; r < 4; ++r) sumexp[m][r] = 0.0f;

    const short* csrc = (const short*)centb;
    for (int t0 = tbase; t0 < tbase + TCHUNK; t0 += 16) {
        // B loads first (4 independent dwordx4)
        bf16x8 bfrag[4];
        const int bbase = (t0 + nIdx) * D_DIM + quad * 8;
        #pragma unroll
        for (int kc = 0; kc < 4; ++kc)
            bfrag[kc] = *(const bf16x8*)(csrc + bbase + kc * 32);

        f32x4 acc[4];
        #pragma unroll
        for (int m = 0; m < 4; ++m) acc[m] = (f32x4){0.f, 0.f, 0.f, 0.f};
        #pragma unroll
        for (int kc = 0; kc < 4; ++kc)
            #pragma unroll
            for (int m = 0; m < 4; ++m)
                acc[m] = __builtin_amdgcn_mfma_f32_16x16x32_bf16(
                    afrag[m][kc], bfrag[kc], acc[m], 0, 0, 0);

        const int t = t0 + nIdx;
        if (t0 <= s0 + 7 && t0 + 16 > s0) {
            // rare tile containing this wave's diagonal band (wave-uniform test)
            #pragma unroll
            for (int m = 0; m < 4; ++m) {
                #pragma unroll
                for (int r = 0; r < 4; ++r) {
                    const int grow = row0 + m * 16 + quad * 4 + r;
                    float l = fmaxf(SCALE * acc[m][r], 1e-6f);
                    if (t == (grow >> 3)) {
                        l = fmaxf(SCALE * cosexc[grow], 1e-6f);
                        plab[grow] = l;           // exactly one writer per row
                    }
                    sumexp[m][r] += __expf(l - SCALE);
                }
            }
        } else {
            #pragma unroll
            for (int m = 0; m < 4; ++m) {
                #pragma unroll
                for (int r = 0; r < 4; ++r) {
                    float l = fmaxf(SCALE * acc[m][r], 1e-6f);
                    sumexp[m][r] += __expf(l - SCALE);
                }
            }
        }
    }

    // reduce across the 16 lanes sharing a quad (they cover t mod 16)
    #pragma unroll
    for (int m = 0; m < 4; ++m) {
        #pragma unroll
        for (int r = 0; r < 4; ++r) {
            #pragma unroll
            for (int msk = 1; msk <= 8; msk <<= 1)
                sumexp[m][r] += __shfl_xor(sumexp[m][r], msk, 64);
        }
    }
    if (nIdx == 0) {
        #pragma unroll
        for (int m = 0; m < 4; ++m)
            #pragma unroll
            for (int r = 0; r < 4; ++r)
                psum[split * N_ROWS + row0 + m * 16 + quad * 4 + r] = sumexp[m][r];
    }
}

// ---------------------------------------------------------------------------
// Kernel C: combine partials -> per-row loss -> per-block partial sum.
// 64 blocks x 256 threads, 1 row/thread. No atomics, no d_out memset needed.
// ---------------------------------------------------------------------------
__global__ __launch_bounds__(256) void combine_kernel(
    const float* __restrict__ psum, const float* __restrict__ plab,
    float* __restrict__ bsum)                  // [64]
{
    __shared__ float red[4];
    const int row = blockIdx.x * 256 + threadIdx.x;

    float s = 0.0f;
    #pragma unroll
    for (int j = 0; j < NSPLIT; ++j) s += psum[j * N_ROWS + row];
    float loss = SCALE + logf(s) - plab[row];   // -logp[row, label]

    float v = wave_allreduce_sum(loss);
    const int wave = threadIdx.x >> 6;
    if ((threadIdx.x & 63) == 0) red[wave] = v;
    __syncthreads();
    if (threadIdx.x == 0)
        bsum[blockIdx.x] = red[0] + red[1] + red[2] + red[3];
}

// ---------------------------------------------------------------------------
// Kernel D: final mean over 64 block partials (one wave).
// ---------------------------------------------------------------------------
__global__ __launch_bounds__(64) void finalize_kernel(
    const float* __restrict__ bsum, float* __restrict__ out)
{
    float v = bsum[threadIdx.x];
    v = wave_allreduce_sum(v);
    if (threadIdx.x == 0) out[0] = v * (1.0f / N_ROWS);
}

extern "C" void kernel_launch(void* const* d_in, const int* in_sizes, int n_in,
                              void* d_out, int out_size, void* d_ws, size_t ws_size,
                              hipStream_t stream) {
    const float* x = (const float*)d_in[0];
    char* ws = (char*)d_ws;

    size_t off = 0;
    __hip_bfloat16* centb = (__hip_bfloat16*)(ws + off); off += (size_t)S_DIM * D_DIM * 2;   // 0.5 MB
    float* cosexc = (float*)(ws + off); off += (size_t)N_ROWS * 4;                            // 64 KB
    float* psum   = (float*)(ws + off); off += (size_t)NSPLIT * N_ROWS * 4;                   // 1 MB
    float* plab   = (float*)(ws + off); off += (size_t)N_ROWS * 4;                            // 64 KB
    float* bsum   = (float*)(ws + off); off += 64 * 4;
    float* out = (float*)d_out;

    prep_kernel<<<S_DIM, 512, 0, stream>>>(x, centb, cosexc);
    score_kernel<<<dim3(N_ROWS / 256, NSPLIT), 256, 0, stream>>>(x, centb, cosexc, psum, plab);
    combine_kernel<<<N_ROWS / 256, 256, 0, stream>>>(psum, plab, bsum);
    finalize_kernel<<<1, 64, 0, stream>>>(bsum, out);
}

// Round 5
// 96.147 us; speedup vs baseline: 1.0482x; 1.0482x over previous
//
#include <hip/hip_runtime.h>
#include <hip/hip_bf16.h>

#define S_DIM 2048
#define G_DIM 8
#define D_DIM 128
#define N_ROWS (S_DIM * G_DIM)   // 16384
#define SCALE 30.0f
#define NSPLIT 16
#define TCHUNK (S_DIM / NSPLIT)  // 128 -> 8 t-tiles of 16 per wave

typedef __attribute__((ext_vector_type(8))) short bf16x8;
typedef __attribute__((ext_vector_type(4))) float f32x4;

__device__ __forceinline__ float wave_allreduce_sum(float v) {
    #pragma unroll
    for (int m = 32; m >= 1; m >>= 1) v += __shfl_xor(v, m, 64);
    return v;
}

// ---------------------------------------------------------------------------
// Kernel A: normalize rows -> bf16 xn (materialized: each row is re-read by
// all 16 splits of score, so precompute once — R4 showed in-kernel
// normalization costs +9us), bf16 normalized centroids, fp32 exclusive-
// centroid cosine. One block per speaker; 8 waves = 8 utterances.
// ---------------------------------------------------------------------------
__global__ __launch_bounds__(512) void prep_kernel(
    const float* __restrict__ x,          // [S][G][D]
    __hip_bfloat16* __restrict__ xnb,     // [S*G][D]
    __hip_bfloat16* __restrict__ centb,   // [S][D]
    float* __restrict__ cosexc)           // [S*G]
{
    __shared__ float xs[G_DIM][D_DIM];
    __shared__ float csum[D_DIM];

    const int s    = blockIdx.x;
    const int g    = threadIdx.x >> 6;
    const int lane = threadIdx.x & 63;
    const int d0 = lane, d1 = lane + 64;

    const float* xr = x + (s * G_DIM + g) * D_DIM;
    float a0 = xr[d0], a1 = xr[d1];

    // row L2 normalize (clip 1e-12)
    float ss  = wave_allreduce_sum(a0 * a0 + a1 * a1);
    float inv = 1.0f / fmaxf(sqrtf(ss), 1e-12f);
    float x0 = a0 * inv, x1 = a1 * inv;

    xs[g][d0] = x0;
    xs[g][d1] = x1;
    __hip_bfloat16* xw = xnb + (s * G_DIM + g) * D_DIM;
    xw[d0] = __float2bfloat16(x0);
    xw[d1] = __float2bfloat16(x1);
    __syncthreads();

    // column sums over g
    if (threadIdx.x < D_DIM) {
        float c = 0.0f;
        #pragma unroll
        for (int gg = 0; gg < G_DIM; ++gg) c += xs[gg][threadIdx.x];
        csum[threadIdx.x] = c;
    }
    __syncthreads();

    // exclusive centroid: (sum - xn)/(G-1), normalize (clip 1e-8), cosine w/ xn
    float e0 = (csum[d0] - x0) * (1.0f / (G_DIM - 1));
    float e1 = (csum[d1] - x1) * (1.0f / (G_DIM - 1));
    float ess = wave_allreduce_sum(e0 * e0 + e1 * e1);
    float ed  = fmaxf(sqrtf(ess), 1e-8f);
    float dot = wave_allreduce_sum(x0 * e0 + x1 * e1);
    if (lane == 0) cosexc[s * G_DIM + g] = dot / ed;

    // centroid: cent = csum/8, cent_n = cent / clip(||cent||, 1e-8)
    if (g == 0) {
        float c0 = csum[d0], c1 = csum[d1];
        float css  = wave_allreduce_sum(c0 * c0 + c1 * c1);
        float cnrm = sqrtf(css) * (1.0f / G_DIM);          // ||cent||
        float scl  = (1.0f / G_DIM) / fmaxf(cnrm, 1e-8f);
        centb[s * D_DIM + d0] = __float2bfloat16(c0 * scl);
        centb[s * D_DIM + d1] = __float2bfloat16(c1 * scl);
    }
}

// ---------------------------------------------------------------------------
// Kernel B: fused scores + softmax-denominator.
// 64 rows/wave (4 A-tiles resident), NSPLIT=16 t-splits, 1024 blocks.
// NEW (R4->R5): explicit software pipeline — next t-tile's 4 B-frags are
// prefetched into separate regs before the current tile's MFMA+epilogue, so
// L2 latency (~300-500cyc) hides under ~250cyc of compute. Prior structure
// was load->wait->mfma->epilogue fully serialized (score ~29us vs ~5us
// floor; MfmaUtil<5%). Reg cost +16 VGPR -> launch_bounds(256,3).
// A-frag (16x16x32): A[m=lane&15][k=(lane>>4)*8+j]. C/D: col=lane&15,
// row=(lane>>4)*4+reg [m89-verified].
// Diagonal band hits exactly one 16-t tile -> wave-uniform branch; plab
// written once by the owning split. logsumexp offset fixed at 30.
// ---------------------------------------------------------------------------
__global__ __launch_bounds__(256, 3) void score_kernel(
    const __hip_bfloat16* __restrict__ xnb,    // [N_ROWS][D]
    const __hip_bfloat16* __restrict__ centb,  // [S][D]
    const float* __restrict__ cosexc,          // [N_ROWS]
    float* __restrict__ psum,                  // [NSPLIT][N_ROWS] partial sum-exp
    float* __restrict__ plab)                  // [N_ROWS] label logit (single owner)
{
    const int wave  = threadIdx.x >> 6;
    const int lane  = threadIdx.x & 63;
    const int row0  = (blockIdx.x * 4 + wave) * 64;   // 64 rows per wave
    const int split = blockIdx.y;
    const int tbase = split * TCHUNK;
    const int tend  = tbase + TCHUNK;
    const int nIdx  = lane & 15;
    const int quad  = lane >> 4;
    const int s0    = row0 >> 3;                      // first speaker of this wave

    // A fragments resident: 4 tiles x 16 rows x 128 k
    const short* xsrc = (const short*)xnb;
    bf16x8 afrag[4][4];
    #pragma unroll
    for (int m = 0; m < 4; ++m) {
        const int abase = (row0 + m * 16 + nIdx) * D_DIM + quad * 8;
        #pragma unroll
        for (int kc = 0; kc < 4; ++kc)
            afrag[m][kc] = *(const bf16x8*)(xsrc + abase + kc * 32);
    }

    float sumexp[4][4];
    #pragma unroll
    for (int m = 0; m < 4; ++m)
        #pragma unroll
        for (int r = 0; r < 4; ++r) sumexp[m][r] = 0.0f;

    const short* csrc = (const short*)centb;

    // prologue: B-frags for first tile
    bf16x8 bcur[4], bnxt[4];
    {
        const int bbase = (tbase + nIdx) * D_DIM + quad * 8;
        #pragma unroll
        for (int kc = 0; kc < 4; ++kc)
            bcur[kc] = *(const bf16x8*)(csrc + bbase + kc * 32);
    }

    for (int t0 = tbase; t0 < tend; t0 += 16) {
        // prefetch next tile's B (wrap-clamped: last iteration re-reads tbase,
        // result unused) — issued before any dependence on bcur's consumers
        const int tn = (t0 + 16 < tend) ? (t0 + 16) : tbase;
        const int nbase = (tn + nIdx) * D_DIM + quad * 8;
        #pragma unroll
        for (int kc = 0; kc < 4; ++kc)
            bnxt[kc] = *(const bf16x8*)(csrc + nbase + kc * 32);

        f32x4 acc[4];
        #pragma unroll
        for (int m = 0; m < 4; ++m) acc[m] = (f32x4){0.f, 0.f, 0.f, 0.f};
        #pragma unroll
        for (int kc = 0; kc < 4; ++kc)
            #pragma unroll
            for (int m = 0; m < 4; ++m)
                acc[m] = __builtin_amdgcn_mfma_f32_16x16x32_bf16(
                    afrag[m][kc], bcur[kc], acc[m], 0, 0, 0);

        const int t = t0 + nIdx;
        if (t0 <= s0 + 7 && t0 + 16 > s0) {
            // rare tile containing this wave's diagonal band (wave-uniform test)
            #pragma unroll
            for (int m = 0; m < 4; ++m) {
                #pragma unroll
                for (int r = 0; r < 4; ++r) {
                    const int grow = row0 + m * 16 + quad * 4 + r;
                    float l = fmaxf(SCALE * acc[m][r], 1e-6f);
                    if (t == (grow >> 3)) {
                        l = fmaxf(SCALE * cosexc[grow], 1e-6f);
                        plab[grow] = l;           // exactly one writer per row
                    }
                    sumexp[m][r] += __expf(l - SCALE);
                }
            }
        } else {
            #pragma unroll
            for (int m = 0; m < 4; ++m) {
                #pragma unroll
                for (int r = 0; r < 4; ++r) {
                    float l = fmaxf(SCALE * acc[m][r], 1e-6f);
                    sumexp[m][r] += __expf(l - SCALE);
                }
            }
        }

        #pragma unroll
        for (int kc = 0; kc < 4; ++kc) bcur[kc] = bnxt[kc];
    }

    // reduce across the 16 lanes sharing a quad (they cover t mod 16)
    #pragma unroll
    for (int m = 0; m < 4; ++m) {
        #pragma unroll
        for (int r = 0; r < 4; ++r) {
            #pragma unroll
            for (int msk = 1; msk <= 8; msk <<= 1)
                sumexp[m][r] += __shfl_xor(sumexp[m][r], msk, 64);
        }
    }
    if (nIdx == 0) {
        #pragma unroll
        for (int m = 0; m < 4; ++m)
            #pragma unroll
            for (int r = 0; r < 4; ++r)
                psum[split * N_ROWS + row0 + m * 16 + quad * 4 + r] = sumexp[m][r];
    }
}

// ---------------------------------------------------------------------------
// Kernel C: combine partials -> per-row loss -> per-block partial sum.
// 64 blocks x 256 threads, 1 row/thread. No atomics, no d_out memset needed.
// ---------------------------------------------------------------------------
__global__ __launch_bounds__(256) void combine_kernel(
    const float* __restrict__ psum, const float* __restrict__ plab,
    float* __restrict__ bsum)                  // [64]
{
    __shared__ float red[4];
    const int row = blockIdx.x * 256 + threadIdx.x;

    float s = 0.0f;
    #pragma unroll
    for (int j = 0; j < NSPLIT; ++j) s += psum[j * N_ROWS + row];
    float loss = SCALE + logf(s) - plab[row];   // -logp[row, label]

    float v = wave_allreduce_sum(loss);
    const int wave = threadIdx.x >> 6;
    if ((threadIdx.x & 63) == 0) red[wave] = v;
    __syncthreads();
    if (threadIdx.x == 0)
        bsum[blockIdx.x] = red[0] + red[1] + red[2] + red[3];
}

// ---------------------------------------------------------------------------
// Kernel D: final mean over 64 block partials (one wave).
// ---------------------------------------------------------------------------
__global__ __launch_bounds__(64) void finalize_kernel(
    const float* __restrict__ bsum, float* __restrict__ out)
{
    float v = bsum[threadIdx.x];
    v = wave_allreduce_sum(v);
    if (threadIdx.x == 0) out[0] = v * (1.0f / N_ROWS);
}

extern "C" void kernel_launch(void* const* d_in, const int* in_sizes, int n_in,
                              void* d_out, int out_size, void* d_ws, size_t ws_size,
                              hipStream_t stream) {
    const float* x = (const float*)d_in[0];
    char* ws = (char*)d_ws;

    size_t off = 0;
    __hip_bfloat16* xnb   = (__hip_bfloat16*)(ws + off); off += (size_t)N_ROWS * D_DIM * 2;  // 4 MB
    __hip_bfloat16* centb = (__hip_bfloat16*)(ws + off); off += (size_t)S_DIM * D_DIM * 2;   // 0.5 MB
    float* cosexc = (float*)(ws + off); off += (size_t)N_ROWS * 4;                            // 64 KB
    float* psum   = (float*)(ws + off); off += (size_t)NSPLIT * N_ROWS * 4;                   // 1 MB
    float* plab   = (float*)(ws + off); off += (size_t)N_ROWS * 4;                            // 64 KB
    float* bsum   = (float*)(ws + off); off += 64 * 4;
    float* out = (float*)d_out;

    prep_kernel<<<S_DIM, 512, 0, stream>>>(x, xnb, centb, cosexc);
    score_kernel<<<dim3(N_ROWS / 256, NSPLIT), 256, 0, stream>>>(xnb, centb, cosexc, psum, plab);
    combine_kernel<<<N_ROWS / 256, 256, 0, stream>>>(psum, plab, bsum);
    finalize_kernel<<<1, 64, 0, stream>>>(bsum, out);
}

// Round 6
// 93.057 us; speedup vs baseline: 1.0831x; 1.0332x over previous
//
#include <hip/hip_runtime.h>
#include <hip/hip_bf16.h>

#define S_DIM 2048
#define G_DIM 8
#define D_DIM 128
#define N_ROWS (S_DIM * G_DIM)   // 16384
#define SCALE 30.0f
#define NSPLIT 16
#define TCHUNK (S_DIM / NSPLIT)  // 128 -> 8 t-tiles of 16 per wave
#define NCOMBINE 64

typedef __attribute__((ext_vector_type(8))) short bf16x8;
typedef __attribute__((ext_vector_type(4))) float f32x4;

__device__ __forceinline__ float wave_allreduce_sum(float v) {
    #pragma unroll
    for (int m = 32; m >= 1; m >>= 1) v += __shfl_xor(v, m, 64);
    return v;
}

// ---------------------------------------------------------------------------
// Kernel A: normalize rows -> bf16 xn (materialized once: R4 showed in-score
// normalization re-pays fp32 reads x NSPLIT, +9us), bf16 normalized
// centroids, fp32 exclusive-centroid cosine. Block 0 also zeroes the final
// accumulator + completion counter (stream-ordered before combine).
// One block per speaker; 8 waves = 8 utterances.
// ---------------------------------------------------------------------------
__global__ __launch_bounds__(512) void prep_kernel(
    const float* __restrict__ x,          // [S][G][D]
    __hip_bfloat16* __restrict__ xnb,     // [S*G][D]
    __hip_bfloat16* __restrict__ centb,   // [S][D]
    float* __restrict__ cosexc,           // [S*G]
    float* __restrict__ acc_out,          // [1] running sum of block losses
    unsigned int* __restrict__ counter)   // [1] combine completion counter
{
    __shared__ float xs[G_DIM][D_DIM];
    __shared__ float csum[D_DIM];

    const int s    = blockIdx.x;
    const int g    = threadIdx.x >> 6;
    const int lane = threadIdx.x & 63;
    const int d0 = lane, d1 = lane + 64;

    if (s == 0 && threadIdx.x == 0) { acc_out[0] = 0.0f; counter[0] = 0u; }

    const float* xr = x + (s * G_DIM + g) * D_DIM;
    float a0 = xr[d0], a1 = xr[d1];

    // row L2 normalize (clip 1e-12)
    float ss  = wave_allreduce_sum(a0 * a0 + a1 * a1);
    float inv = 1.0f / fmaxf(sqrtf(ss), 1e-12f);
    float x0 = a0 * inv, x1 = a1 * inv;

    xs[g][d0] = x0;
    xs[g][d1] = x1;
    __hip_bfloat16* xw = xnb + (s * G_DIM + g) * D_DIM;
    xw[d0] = __float2bfloat16(x0);
    xw[d1] = __float2bfloat16(x1);
    __syncthreads();

    // column sums over g
    if (threadIdx.x < D_DIM) {
        float c = 0.0f;
        #pragma unroll
        for (int gg = 0; gg < G_DIM; ++gg) c += xs[gg][threadIdx.x];
        csum[threadIdx.x] = c;
    }
    __syncthreads();

    // exclusive centroid: (sum - xn)/(G-1), normalize (clip 1e-8), cosine w/ xn
    float e0 = (csum[d0] - x0) * (1.0f / (G_DIM - 1));
    float e1 = (csum[d1] - x1) * (1.0f / (G_DIM - 1));
    float ess = wave_allreduce_sum(e0 * e0 + e1 * e1);
    float ed  = fmaxf(sqrtf(ess), 1e-8f);
    float dot = wave_allreduce_sum(x0 * e0 + x1 * e1);
    if (lane == 0) cosexc[s * G_DIM + g] = dot / ed;

    // centroid: cent = csum/8, cent_n = cent / clip(||cent||, 1e-8)
    if (g == 0) {
        float c0 = csum[d0], c1 = csum[d1];
        float css  = wave_allreduce_sum(c0 * c0 + c1 * c1);
        float cnrm = sqrtf(css) * (1.0f / G_DIM);          // ||cent||
        float scl  = (1.0f / G_DIM) / fmaxf(cnrm, 1e-8f);
        centb[s * D_DIM + d0] = __float2bfloat16(c0 * scl);
        centb[s * D_DIM + d1] = __float2bfloat16(c1 * scl);
    }
}

// ---------------------------------------------------------------------------
// Kernel B: fused scores + softmax-denominator. KNOWN-BEST config (92us
// total): 64 rows/wave (4 A-tiles resident), NSPLIT=16, 1024 blocks = 4/CU,
// launch_bounds(256,4). R5 showed register prefetch + (256,3) regresses
// (-1 block/CU outweighs ILP gain) — do not re-add.
// A-frag (16x16x32): A[m=lane&15][k=(lane>>4)*8+j]. C/D: col=lane&15,
// row=(lane>>4)*4+reg [m89-verified].
// Diagonal band hits exactly one 16-t tile -> wave-uniform branch; plab
// written once by the owning split. logsumexp offset fixed at 30 (logits in
// (0,30]): no max pass.
// ---------------------------------------------------------------------------
__global__ __launch_bounds__(256, 4) void score_kernel(
    const __hip_bfloat16* __restrict__ xnb,    // [N_ROWS][D]
    const __hip_bfloat16* __restrict__ centb,  // [S][D]
    const float* __restrict__ cosexc,          // [N_ROWS]
    float* __restrict__ psum,                  // [NSPLIT][N_ROWS] partial sum-exp
    float* __restrict__ plab)                  // [N_ROWS] label logit (single owner)
{
    const int wave  = threadIdx.x >> 6;
    const int lane  = threadIdx.x & 63;
    const int row0  = (blockIdx.x * 4 + wave) * 64;   // 64 rows per wave
    const int split = blockIdx.y;
    const int tbase = split * TCHUNK;
    const int nIdx  = lane & 15;
    const int quad  = lane >> 4;
    const int s0    = row0 >> 3;                      // first speaker of this wave

    // A fragments resident: 4 tiles x 16 rows x 128 k
    const short* xsrc = (const short*)xnb;
    bf16x8 afrag[4][4];
    #pragma unroll
    for (int m = 0; m < 4; ++m) {
        const int abase = (row0 + m * 16 + nIdx) * D_DIM + quad * 8;
        #pragma unroll
        for (int kc = 0; kc < 4; ++kc)
            afrag[m][kc] = *(const bf16x8*)(xsrc + abase + kc * 32);
    }

    float sumexp[4][4];
    #pragma unroll
    for (int m = 0; m < 4; ++m)
        #pragma unroll
        for (int r = 0; r < 4; ++r) sumexp[m][r] = 0.0f;

    const short* csrc = (const short*)centb;
    for (int t0 = tbase; t0 < tbase + TCHUNK; t0 += 16) {
        // B loads (4 independent dwordx4)
        bf16x8 bfrag[4];
        const int bbase = (t0 + nIdx) * D_DIM + quad * 8;
        #pragma unroll
        for (int kc = 0; kc < 4; ++kc)
            bfrag[kc] = *(const bf16x8*)(csrc + bbase + kc * 32);

        f32x4 acc[4];
        #pragma unroll
        for (int m = 0; m < 4; ++m) acc[m] = (f32x4){0.f, 0.f, 0.f, 0.f};
        #pragma unroll
        for (int kc = 0; kc < 4; ++kc)
            #pragma unroll
            for (int m = 0; m < 4; ++m)
                acc[m] = __builtin_amdgcn_mfma_f32_16x16x32_bf16(
                    afrag[m][kc], bfrag[kc], acc[m], 0, 0, 0);

        const int t = t0 + nIdx;
        if (t0 <= s0 + 7 && t0 + 16 > s0) {
            // rare tile containing this wave's diagonal band (wave-uniform test)
            #pragma unroll
            for (int m = 0; m < 4; ++m) {
                #pragma unroll
                for (int r = 0; r < 4; ++r) {
                    const int grow = row0 + m * 16 + quad * 4 + r;
                    float l = fmaxf(SCALE * acc[m][r], 1e-6f);
                    if (t == (grow >> 3)) {
                        l = fmaxf(SCALE * cosexc[grow], 1e-6f);
                        plab[grow] = l;           // exactly one writer per row
                    }
                    sumexp[m][r] += __expf(l - SCALE);
                }
            }
        } else {
            #pragma unroll
            for (int m = 0; m < 4; ++m) {
                #pragma unroll
                for (int r = 0; r < 4; ++r) {
                    float l = fmaxf(SCALE * acc[m][r], 1e-6f);
                    sumexp[m][r] += __expf(l - SCALE);
                }
            }
        }
    }

    // reduce across the 16 lanes sharing a quad (they cover t mod 16)
    #pragma unroll
    for (int m = 0; m < 4; ++m) {
        #pragma unroll
        for (int r = 0; r < 4; ++r) {
            #pragma unroll
            for (int msk = 1; msk <= 8; msk <<= 1)
                sumexp[m][r] += __shfl_xor(sumexp[m][r], msk, 64);
        }
    }
    if (nIdx == 0) {
        #pragma unroll
        for (int m = 0; m < 4; ++m)
            #pragma unroll
            for (int r = 0; r < 4; ++r)
                psum[split * N_ROWS + row0 + m * 16 + quad * 4 + r] = sumexp[m][r];
    }
}

// ---------------------------------------------------------------------------
// Kernel C: combine partials -> per-row loss -> block sum -> device-scope
// atomic accumulate; LAST block (counter) writes the mean to d_out.
// Saves the finalize dispatch + its graph gap. acc/counter zeroed by prep
// (stream-ordered). atomicAdd is device-scope by default [m20]; counter
// RMW order + threadfence make all 64 adds visible to the last block.
// ---------------------------------------------------------------------------
__global__ __launch_bounds__(256) void combine_kernel(
    const float* __restrict__ psum, const float* __restrict__ plab,
    float* __restrict__ acc_out, unsigned int* __restrict__ counter,
    float* __restrict__ out)
{
    __shared__ float red[4];
    const int row = blockIdx.x * 256 + threadIdx.x;

    float s = 0.0f;
    #pragma unroll
    for (int j = 0; j < NSPLIT; ++j) s += psum[j * N_ROWS + row];
    float loss = SCALE + logf(s) - plab[row];   // -logp[row, label]

    float v = wave_allreduce_sum(loss);
    const int wave = threadIdx.x >> 6;
    if ((threadIdx.x & 63) == 0) red[wave] = v;
    __syncthreads();
    if (threadIdx.x == 0) {
        atomicAdd(acc_out, red[0] + red[1] + red[2] + red[3]);
        __threadfence();
        unsigned int prev = atomicAdd(counter, 1u);
        if (prev == NCOMBINE - 1) {
            float total = atomicAdd(acc_out, 0.0f);   // coherent read
            out[0] = total * (1.0f / N_ROWS);
        }
    }
}

extern "C" void kernel_launch(void* const* d_in, const int* in_sizes, int n_in,
                              void* d_out, int out_size, void* d_ws, size_t ws_size,
                              hipStream_t stream) {
    const float* x = (const float*)d_in[0];
    char* ws = (char*)d_ws;

    size_t off = 0;
    __hip_bfloat16* xnb   = (__hip_bfloat16*)(ws + off); off += (size_t)N_ROWS * D_DIM * 2;  // 4 MB
    __hip_bfloat16* centb = (__hip_bfloat16*)(ws + off); off += (size_t)S_DIM * D_DIM * 2;   // 0.5 MB
    float* cosexc = (float*)(ws + off); off += (size_t)N_ROWS * 4;                            // 64 KB
    float* psum   = (float*)(ws + off); off += (size_t)NSPLIT * N_ROWS * 4;                   // 1 MB
    float* plab   = (float*)(ws + off); off += (size_t)N_ROWS * 4;                            // 64 KB
    float* acc    = (float*)(ws + off); off += 4;
    unsigned int* counter = (unsigned int*)(ws + off); off += 4;
    float* out = (float*)d_out;

    prep_kernel<<<S_DIM, 512, 0, stream>>>(x, xnb, centb, cosexc, acc, counter);
    score_kernel<<<dim3(N_ROWS / 256, NSPLIT), 256, 0, stream>>>(xnb, centb, cosexc, psum, plab);
    combine_kernel<<<NCOMBINE, 256, 0, stream>>>(psum, plab, acc, counter, out);
}

// Round 7
// 83.116 us; speedup vs baseline: 1.2126x; 1.1196x over previous
//
#include <hip/hip_runtime.h>
#include <hip/hip_bf16.h>

#define S_DIM 2048
#define G_DIM 8
#define D_DIM 128
#define N_ROWS (S_DIM * G_DIM)   // 16384
#define SCALE 30.0f
#define NSPLIT 16
#define TCHUNK (S_DIM / NSPLIT)  // 128 speakers per block -> 32 KB LDS tile
#define NCOMBINE 64

typedef __attribute__((ext_vector_type(8))) short bf16x8;
typedef __attribute__((ext_vector_type(4))) float f32x4;

__device__ __forceinline__ float wave_allreduce_sum(float v) {
    #pragma unroll
    for (int m = 32; m >= 1; m >>= 1) v += __shfl_xor(v, m, 64);
    return v;
}

// ---------------------------------------------------------------------------
// Kernel A: normalize rows -> bf16 xn (materialized once; R4: in-score
// normalization re-pays fp32 reads x NSPLIT, +9us), bf16 normalized
// centroids, fp32 exclusive-centroid cosine. Block 0 zeroes the final
// accumulator + completion counter (stream-ordered before combine).
// ---------------------------------------------------------------------------
__global__ __launch_bounds__(512) void prep_kernel(
    const float* __restrict__ x,          // [S][G][D]
    __hip_bfloat16* __restrict__ xnb,     // [S*G][D]
    __hip_bfloat16* __restrict__ centb,   // [S][D]
    float* __restrict__ cosexc,           // [S*G]
    float* __restrict__ acc_out,          // [1]
    unsigned int* __restrict__ counter)   // [1]
{
    __shared__ float xs[G_DIM][D_DIM];
    __shared__ float csum[D_DIM];

    const int s    = blockIdx.x;
    const int g    = threadIdx.x >> 6;
    const int lane = threadIdx.x & 63;
    const int d0 = lane, d1 = lane + 64;

    if (s == 0 && threadIdx.x == 0) { acc_out[0] = 0.0f; counter[0] = 0u; }

    const float* xr = x + (s * G_DIM + g) * D_DIM;
    float a0 = xr[d0], a1 = xr[d1];

    float ss  = wave_allreduce_sum(a0 * a0 + a1 * a1);
    float inv = 1.0f / fmaxf(sqrtf(ss), 1e-12f);
    float x0 = a0 * inv, x1 = a1 * inv;

    xs[g][d0] = x0;
    xs[g][d1] = x1;
    __hip_bfloat16* xw = xnb + (s * G_DIM + g) * D_DIM;
    xw[d0] = __float2bfloat16(x0);
    xw[d1] = __float2bfloat16(x1);
    __syncthreads();

    if (threadIdx.x < D_DIM) {
        float c = 0.0f;
        #pragma unroll
        for (int gg = 0; gg < G_DIM; ++gg) c += xs[gg][threadIdx.x];
        csum[threadIdx.x] = c;
    }
    __syncthreads();

    float e0 = (csum[d0] - x0) * (1.0f / (G_DIM - 1));
    float e1 = (csum[d1] - x1) * (1.0f / (G_DIM - 1));
    float ess = wave_allreduce_sum(e0 * e0 + e1 * e1);
    float ed  = fmaxf(sqrtf(ess), 1e-8f);
    float dot = wave_allreduce_sum(x0 * e0 + x1 * e1);
    if (lane == 0) cosexc[s * G_DIM + g] = dot / ed;

    if (g == 0) {
        float c0 = csum[d0], c1 = csum[d1];
        float css  = wave_allreduce_sum(c0 * c0 + c1 * c1);
        float cnrm = sqrtf(css) * (1.0f / G_DIM);
        float scl  = (1.0f / G_DIM) / fmaxf(cnrm, 1e-8f);
        centb[s * D_DIM + d0] = __float2bfloat16(c0 * scl);
        centb[s * D_DIM + d1] = __float2bfloat16(c1 * scl);
    }
}

// ---------------------------------------------------------------------------
// Kernel B: fused scores + softmax-denominator.
// R6->R7: B-chunk (128 centroids = 32 KB) staged into LDS ONCE per block via
// global_load_lds width=16, then the 8 MFMA iterations are fed by
// ds_read_b128 (no barrier inside the loop -> pipelinable; global B latency
// eliminated; 4x intra-block B redundancy eliminated).
// Bank-conflict note: global_load_lds forces identity LDS layout (wave-
// uniform base + lane*16, no padding possible), and the natural read pattern
// (16 lanes/quad -> same 4 banks) would be a 16-way conflict (5.7x, m136).
// Fix: permute the GLOBAL source during staging — LDS slot (r, cc) holds
// global chunk (cc - r) & 15; readers fetch cc = (c' + r) & 15. Read banks:
// ((c'+r)&7)*4 -> 2-way aliasing = free [m136].
// A-frag (16x16x32): A[m=lane&15][k=(lane>>4)*8+j]. C/D: col=lane&15,
// row=(lane>>4)*4+reg [m89-verified]. Diagonal band hits exactly one 16-t
// tile -> wave-uniform branch; plab written once by the owning split.
// logsumexp offset fixed at 30 (logits in (0,30]): no max pass.
// (256,4): R5 showed (256,3)+reg-prefetch regresses — do not re-add.
// ---------------------------------------------------------------------------
__global__ __launch_bounds__(256, 4) void score_kernel(
    const __hip_bfloat16* __restrict__ xnb,    // [N_ROWS][D]
    const __hip_bfloat16* __restrict__ centb,  // [S][D]
    const float* __restrict__ cosexc,          // [N_ROWS]
    float* __restrict__ psum,                  // [NSPLIT][N_ROWS]
    float* __restrict__ plab)                  // [N_ROWS]
{
    __shared__ short bsm[TCHUNK * D_DIM];      // 32 KB, source-permuted

    const int wave  = threadIdx.x >> 6;
    const int lane  = threadIdx.x & 63;
    const int tid   = threadIdx.x;
    const int row0  = (blockIdx.x * 4 + wave) * 64;   // 64 rows per wave
    const int split = blockIdx.y;
    const int tbase = split * TCHUNK;
    const int nIdx  = lane & 15;
    const int quad  = lane >> 4;
    const int s0    = row0 >> 3;

    // ---- stage B tile into LDS (16B/lane x 8 slots/thread), permuted ----
    {
        const short* gsrc = (const short*)centb;
        #pragma unroll
        for (int j = 0; j < 8; ++j) {
            const int s  = j * 256 + tid;     // slot index (16B slots)
            const int r  = s >> 4;            // local speaker row 0..127
            const int cc = s & 15;            // LDS chunk column
            const int c  = (cc - r) & 15;     // global chunk held in this slot
            const short* g = gsrc + (size_t)(tbase + r) * D_DIM + c * 8;
            __builtin_amdgcn_global_load_lds(
                (const __attribute__((address_space(1))) void*)g,
                (__attribute__((address_space(3))) void*)
                    ((char*)bsm + j * 4096 + wave * 1024),
                16, 0, 0);
        }
    }

    // ---- A fragments resident: 4 tiles x 16 rows x 128 k (global loads,
    //      independent of staging; barrier below waits both) ----
    const short* xsrc = (const short*)xnb;
    bf16x8 afrag[4][4];
    #pragma unroll
    for (int m = 0; m < 4; ++m) {
        const int abase = (row0 + m * 16 + nIdx) * D_DIM + quad * 8;
        #pragma unroll
        for (int kc = 0; kc < 4; ++kc)
            afrag[m][kc] = *(const bf16x8*)(xsrc + abase + kc * 32);
    }

    float sumexp[4][4];
    #pragma unroll
    for (int m = 0; m < 4; ++m)
        #pragma unroll
        for (int r = 0; r < 4; ++r) sumexp[m][r] = 0.0f;

    __syncthreads();   // staging complete (implicit vmcnt drain)

    for (int t0 = tbase; t0 < tbase + TCHUNK; t0 += 16) {
        const int lr = (t0 - tbase) + nIdx;    // local B row 0..127
        bf16x8 bfrag[4];
        #pragma unroll
        for (int kc = 0; kc < 4; ++kc) {
            const int cc = (quad + kc * 4 + lr) & 15;   // inverse rotation
            bfrag[kc] = *(const bf16x8*)(bsm + lr * D_DIM + cc * 8);
        }

        f32x4 acc[4];
        #pragma unroll
        for (int m = 0; m < 4; ++m) acc[m] = (f32x4){0.f, 0.f, 0.f, 0.f};
        #pragma unroll
        for (int kc = 0; kc < 4; ++kc)
            #pragma unroll
            for (int m = 0; m < 4; ++m)
                acc[m] = __builtin_amdgcn_mfma_f32_16x16x32_bf16(
                    afrag[m][kc], bfrag[kc], acc[m], 0, 0, 0);

        const int t = t0 + nIdx;
        if (t0 <= s0 + 7 && t0 + 16 > s0) {
            // rare tile containing this wave's diagonal band (wave-uniform)
            #pragma unroll
            for (int m = 0; m < 4; ++m) {
                #pragma unroll
                for (int r = 0; r < 4; ++r) {
                    const int grow = row0 + m * 16 + quad * 4 + r;
                    float l = fmaxf(SCALE * acc[m][r], 1e-6f);
                    if (t == (grow >> 3)) {
                        l = fmaxf(SCALE * cosexc[grow], 1e-6f);
                        plab[grow] = l;           // exactly one writer per row
                    }
                    sumexp[m][r] += __expf(l - SCALE);
                }
            }
        } else {
            #pragma unroll
            for (int m = 0; m < 4; ++m) {
                #pragma unroll
                for (int r = 0; r < 4; ++r) {
                    // exp(clamp(30a,1e-6)-30) == exp(max(30a-30, 1e-6-30))
                    float e = fmaxf(fmaf(SCALE, acc[m][r], -SCALE), 1e-6f - SCALE);
                    sumexp[m][r] += __expf(e);
                }
            }
        }
    }

    // reduce across the 16 lanes sharing a quad (they cover t mod 16)
    #pragma unroll
    for (int m = 0; m < 4; ++m) {
        #pragma unroll
        for (int r = 0; r < 4; ++r) {
            #pragma unroll
            for (int msk = 1; msk <= 8; msk <<= 1)
                sumexp[m][r] += __shfl_xor(sumexp[m][r], msk, 64);
        }
    }
    if (nIdx == 0) {
        #pragma unroll
        for (int m = 0; m < 4; ++m)
            #pragma unroll
            for (int r = 0; r < 4; ++r)
                psum[split * N_ROWS + row0 + m * 16 + quad * 4 + r] = sumexp[m][r];
    }
}

// ---------------------------------------------------------------------------
// Kernel C: combine partials -> per-row loss -> block sum -> device-scope
// atomic accumulate; LAST block writes the mean to d_out. [m20] atomics are
// device-scope; counter RMW + threadfence order the adds.
// ---------------------------------------------------------------------------
__global__ __launch_bounds__(256) void combine_kernel(
    const float* __restrict__ psum, const float* __restrict__ plab,
    float* __restrict__ acc_out, unsigned int* __restrict__ counter,
    float* __restrict__ out)
{
    __shared__ float red[4];
    const int row = blockIdx.x * 256 + threadIdx.x;

    float s = 0.0f;
    #pragma unroll
    for (int j = 0; j < NSPLIT; ++j) s += psum[j * N_ROWS + row];
    float loss = SCALE + logf(s) - plab[row];   // -logp[row, label]

    float v = wave_allreduce_sum(loss);
    const int wave = threadIdx.x >> 6;
    if ((threadIdx.x & 63) == 0) red[wave] = v;
    __syncthreads();
    if (threadIdx.x == 0) {
        atomicAdd(acc_out, red[0] + red[1] + red[2] + red[3]);
        __threadfence();
        unsigned int prev = atomicAdd(counter, 1u);
        if (prev == NCOMBINE - 1) {
            float total = atomicAdd(acc_out, 0.0f);   // coherent read
            out[0] = total * (1.0f / N_ROWS);
        }
    }
}

extern "C" void kernel_launch(void* const* d_in, const int* in_sizes, int n_in,
                              void* d_out, int out_size, void* d_ws, size_t ws_size,
                              hipStream_t stream) {
    const float* x = (const float*)d_in[0];
    char* ws = (char*)d_ws;

    size_t off = 0;
    __hip_bfloat16* xnb   = (__hip_bfloat16*)(ws + off); off += (size_t)N_ROWS * D_DIM * 2;  // 4 MB
    __hip_bfloat16* centb = (__hip_bfloat16*)(ws + off); off += (size_t)S_DIM * D_DIM * 2;   // 0.5 MB
    float* cosexc = (float*)(ws + off); off += (size_t)N_ROWS * 4;                            // 64 KB
    float* psum   = (float*)(ws + off); off += (size_t)NSPLIT * N_ROWS * 4;                   // 1 MB
    float* plab   = (float*)(ws + off); off += (size_t)N_ROWS * 4;                            // 64 KB
    float* acc    = (float*)(ws + off); off += 4;
    unsigned int* counter = (unsigned int*)(ws + off); off += 4;
    float* out = (float*)d_out;

    prep_kernel<<<S_DIM, 512, 0, stream>>>(x, xnb, centb, cosexc, acc, counter);
    score_kernel<<<dim3(N_ROWS / 256, NSPLIT), 256, 0, stream>>>(xnb, centb, cosexc, psum, plab);
    combine_kernel<<<NCOMBINE, 256, 0, stream>>>(psum, plab, acc, counter, out);
}